// Round 8
// baseline (63.717 us; speedup 1.0000x reference)
//
#include <hip/hip_runtime.h>
#include <math.h>

typedef float f4 __attribute__((ext_vector_type(4)));
typedef _Float16 h8 __attribute__((ext_vector_type(8)));

struct F3 { float x, y, z; };

__device__ __forceinline__ F3 f3(float x, float y, float z) { return {x, y, z}; }
__device__ __forceinline__ F3 add(F3 a, F3 b) { return {a.x+b.x, a.y+b.y, a.z+b.z}; }
__device__ __forceinline__ F3 sub(F3 a, F3 b) { return {a.x-b.x, a.y-b.y, a.z-b.z}; }
__device__ __forceinline__ F3 mul(F3 a, float s) { return {a.x*s, a.y*s, a.z*s}; }
__device__ __forceinline__ float dot3(F3 a, F3 b) { return a.x*b.x + a.y*b.y + a.z*b.z; }
__device__ __forceinline__ F3 cross3(F3 a, F3 b) {
    return {a.y*b.z - a.z*b.y, a.z*b.x - a.x*b.z, a.x*b.y - a.y*b.x};
}
__device__ __forceinline__ F3 safe_normalize(F3 a) {
    float d = dot3(a, a);
    float inv = rsqrtf(fmaxf(d, 1e-20f));
    return mul(a, inv);
}

#define BLK 256

// ---------------------------------------------------------------------------
// Kernel 1: per-face geometry -> ONE 16B record per face (8 x fp16):
//   { fc.x, fc.y, fc.z, fs, qw, qx, qy, qz }  with R(q) = [a0 | a1 | a2]
// 159 KB table: L2-resident. One dwordx4 gather per point.
// ---------------------------------------------------------------------------
__global__ __launch_bounds__(BLK) void face_precompute_kernel(
    const float* __restrict__ verts, const int* __restrict__ faces,
    h8* __restrict__ tab, int F)
{
    const int f = blockIdx.x * BLK + threadIdx.x;
    if (f >= F) return;
    const int f0 = faces[3*f+0], f1 = faces[3*f+1], f2 = faces[3*f+2];
    const F3 v0 = f3(verts[3*f0], verts[3*f0+1], verts[3*f0+2]);
    const F3 v1 = f3(verts[3*f1], verts[3*f1+1], verts[3*f1+2]);
    const F3 v2 = f3(verts[3*f2], verts[3*f2+1], verts[3*f2+2]);

    const F3 fc  = mul(add(add(v0, v1), v2), (1.0f/3.0f));
    const F3 e01 = sub(v1, v0);
    const F3 e02 = sub(v2, v0);
    const F3 a0 = safe_normalize(e01);
    const F3 a1 = safe_normalize(cross3(a0, e02));
    const F3 a2 = mul(safe_normalize(cross3(a1, a0)), -1.0f);
    const float s0 = sqrtf(dot3(e01, e01));
    const float s1 = fabsf(dot3(a2, e02));
    const float fs = 0.5f * (s0 + s1);

    // rotation matrix with columns a0,a1,a2 -> quaternion (w,x,y,z)
    const float R00 = a0.x, R10 = a0.y, R20 = a0.z;
    const float R01 = a1.x, R11 = a1.y, R21 = a1.z;
    const float R02 = a2.x, R12 = a2.y, R22 = a2.z;
    float qw, qx, qy, qz;
    const float tr = R00 + R11 + R22;
    if (tr > 0.0f) {
        const float s = 0.5f / sqrtf(tr + 1.0f);
        qw = 0.25f / s;
        qx = (R21 - R12) * s;
        qy = (R02 - R20) * s;
        qz = (R10 - R01) * s;
    } else if (R00 > R11 && R00 > R22) {
        const float s = 2.0f * sqrtf(1.0f + R00 - R11 - R22);
        qw = (R21 - R12) / s;
        qx = 0.25f * s;
        qy = (R01 + R10) / s;
        qz = (R02 + R20) / s;
    } else if (R11 > R22) {
        const float s = 2.0f * sqrtf(1.0f + R11 - R00 - R22);
        qw = (R02 - R20) / s;
        qx = (R01 + R10) / s;
        qy = 0.25f * s;
        qz = (R12 + R21) / s;
    } else {
        const float s = 2.0f * sqrtf(1.0f + R22 - R00 - R11);
        qw = (R10 - R01) / s;
        qx = (R02 + R20) / s;
        qy = (R12 + R21) / s;
        qz = 0.25f * s;
    }
    const float qn = rsqrtf(fmaxf(qw*qw + qx*qx + qy*qy + qz*qz, 1e-30f));
    qw *= qn; qx *= qn; qy *= qn; qz *= qn;

    h8 rec;
    rec[0] = (_Float16)fc.x; rec[1] = (_Float16)fc.y;
    rec[2] = (_Float16)fc.z; rec[3] = (_Float16)fs;
    rec[4] = (_Float16)qw;   rec[5] = (_Float16)qx;
    rec[6] = (_Float16)qy;   rec[7] = (_Float16)qz;
    tab[f] = rec;
}

// ---------------------------------------------------------------------------
// per-point math: all named scalars (no runtime-indexed arrays anywhere)
// ---------------------------------------------------------------------------
struct Out13 {
    float o0,o1,o2,o3,o4,o5,o6,o7,o8,o9,o10,o11,o12;
};

__device__ __forceinline__ Out13 compute_point(
    float px, float py, float pz,
    float rw, float rx, float ry, float rz,
    float sc0, float sc1, float sc2,
    float opa, float d0, float d1, float d2,
    h8 rec)
{
    const float fcx = (float)rec[0], fcy = (float)rec[1], fcz = (float)rec[2];
    const float fs  = (float)rec[3];
    const float fw  = (float)rec[4], fx = (float)rec[5];
    const float fy  = (float)rec[6], fz = (float)rec[7];

    // xyz_out = (R(qf)*p)*fs + fc ;  v = p + fw*t + qv x t, t = 2 qv x p
    const float ttx = 2.0f*(fy*pz - fz*py);
    const float tty = 2.0f*(fz*px - fx*pz);
    const float ttz = 2.0f*(fx*py - fy*px);
    const float vx = px + fw*ttx + (fy*ttz - fz*tty);
    const float vy = py + fw*tty + (fz*ttx - fx*ttz);
    const float vz = pz + fw*ttz + (fx*tty - fy*ttx);

    // normalize point quaternion (rsqrt; ref adds 1e-12 to |q| -> ~1e-7 diff)
    const float qd = rw*rw + rx*rx + ry*ry + rz*rz;
    const float qi = rsqrtf(fmaxf(qd, 1e-24f));
    const float pw = rw*qi, pxq = rx*qi, pyq = ry*qi, pzq = rz*qi;

    // qt = qf (Hamilton) qp  ->  R(qt) = O * Q
    const float tw = fw*pw  - fx*pxq - fy*pyq - fz*pzq;
    const float tx = fw*pxq + fx*pw  + fy*pzq - fz*pyq;
    const float ty = fw*pyq - fx*pzq + fy*pw  + fz*pxq;
    const float tz = fw*pzq + fx*pyq - fy*pxq + fz*pw;

    // M = R(qt) columns
    const float m0x = 1.0f - 2.0f*(ty*ty + tz*tz);
    const float m0y = 2.0f*(tx*ty + tz*tw);
    const float m0z = 2.0f*(tx*tz - ty*tw);
    const float m1x = 2.0f*(tx*ty - tz*tw);
    const float m1y = 1.0f - 2.0f*(tx*tx + tz*tz);
    const float m1z = 2.0f*(ty*tz + tx*tw);
    const float m2x = 2.0f*(tx*tz + ty*tw);
    const float m2y = 2.0f*(ty*tz - tx*tw);
    const float m2z = 1.0f - 2.0f*(tx*tx + ty*ty);

    const float w0 = __expf(sc0) * fs;
    const float w1 = __expf(sc1) * fs;
    const float w2 = __expf(sc2) * fs;
    const float t0s = w0*w0, t1s = w1*w1, t2s = w2*w2;

    Out13 o;
    o.o0 = vx*fs + fcx;
    o.o1 = vy*fs + fcy;
    o.o2 = vz*fs + fcz;
    o.o3 = fminf(fmaxf((0.5f + 0.282f*d0) * 255.0f, 0.0f), 255.0f);
    o.o4 = fminf(fmaxf((0.5f + 0.282f*d1) * 255.0f, 0.0f), 255.0f);
    o.o5 = fminf(fmaxf((0.5f + 0.282f*d2) * 255.0f, 0.0f), 255.0f);
    const float sg = 1.0f / (1.0f + __expf(-opa));
    o.o6 = fminf(fmaxf(sg * 255.0f, 0.0f), 255.0f);
    o.o7  = t0s*m0x*m0x + t1s*m1x*m1x + t2s*m2x*m2x;
    o.o8  = t0s*m0x*m0y + t1s*m1x*m1y + t2s*m2x*m2y;
    o.o9  = t0s*m0x*m0z + t1s*m1x*m1z + t2s*m2x*m2z;
    o.o10 = t0s*m0y*m0y + t1s*m1y*m1y + t2s*m2y*m2y;
    o.o11 = t0s*m0y*m0z + t1s*m1y*m1z + t2s*m2y*m2z;
    o.o12 = t0s*m0z*m0z + t1s*m1z*m1z + t2s*m2z*m2z;
    return o;
}

__device__ __forceinline__ f4 mkf4(float a, float b, float c, float d) {
    f4 v; v.x = a; v.y = b; v.z = c; v.w = d; return v;
}

// ---------------------------------------------------------------------------
// Kernel 2: FOUR points/thread, everything named-scalar. 15 dwordx4 stream
// loads + 4 dwordx4 gathers in, 13 dwordx4 direct stores out (52 contiguous
// floats per thread, 16B aligned). No LDS, no barriers.
// ---------------------------------------------------------------------------
__global__ __launch_bounds__(BLK) void gauss_main4_kernel(
    const h8*    __restrict__ tab,       // (F,) 16B records
    const int*   __restrict__ binding,   // (N,)
    const float* __restrict__ xyz,       // (N,3)
    const float* __restrict__ rot,       // (N,4)
    const float* __restrict__ scal,      // (N,3)
    const float* __restrict__ opac,      // (N,1)
    const float* __restrict__ fdc,       // (N,1,3)
    float*       __restrict__ out,       // (N,13)
    int N)
{
    const int t  = blockIdx.x * BLK + threadIdx.x;
    const int NT = (N + 3) >> 2;
    if (t >= NT) return;
    const int p0 = 4 * t;

    if (p0 + 3 < N) {
        const int4 b4 = reinterpret_cast<const int4*>(binding)[t];
        // xyz: 12 floats = 3 x f4
        const f4 xa = reinterpret_cast<const f4*>(xyz)[3*t    ];  // p0.xyz p1.x
        const f4 xb = reinterpret_cast<const f4*>(xyz)[3*t + 1]; // p1.yz p2.xy
        const f4 xc = reinterpret_cast<const f4*>(xyz)[3*t + 2]; // p2.z p3.xyz
        const f4 sa = reinterpret_cast<const f4*>(scal)[3*t    ];
        const f4 sb = reinterpret_cast<const f4*>(scal)[3*t + 1];
        const f4 sc = reinterpret_cast<const f4*>(scal)[3*t + 2];
        const f4 da = reinterpret_cast<const f4*>(fdc)[3*t    ];
        const f4 db = reinterpret_cast<const f4*>(fdc)[3*t + 1];
        const f4 dc = reinterpret_cast<const f4*>(fdc)[3*t + 2];
        const f4 qA = reinterpret_cast<const f4*>(rot)[4*t    ];
        const f4 qB = reinterpret_cast<const f4*>(rot)[4*t + 1];
        const f4 qC = reinterpret_cast<const f4*>(rot)[4*t + 2];
        const f4 qD = reinterpret_cast<const f4*>(rot)[4*t + 3];
        const f4 op4 = reinterpret_cast<const f4*>(opac)[t];
        const h8 recA = tab[b4.x];
        const h8 recB = tab[b4.y];
        const h8 recC = tab[b4.z];
        const h8 recD = tab[b4.w];

        const Out13 A = compute_point(xa.x, xa.y, xa.z,
                                      qA.x, qA.y, qA.z, qA.w,
                                      sa.x, sa.y, sa.z,
                                      op4.x, da.x, da.y, da.z, recA);
        const Out13 B = compute_point(xa.w, xb.x, xb.y,
                                      qB.x, qB.y, qB.z, qB.w,
                                      sa.w, sb.x, sb.y,
                                      op4.y, da.w, db.x, db.y, recB);
        const Out13 C = compute_point(xb.z, xb.w, xc.x,
                                      qC.x, qC.y, qC.z, qC.w,
                                      sb.z, sb.w, sc.x,
                                      op4.z, db.z, db.w, dc.x, recC);
        const Out13 D = compute_point(xc.y, xc.z, xc.w,
                                      qD.x, qD.y, qD.z, qD.w,
                                      sc.y, sc.z, sc.w,
                                      op4.w, dc.y, dc.z, dc.w, recD);

        // 13 direct dwordx4 stores: 52 contiguous floats at out + t*52
        f4* o4 = reinterpret_cast<f4*>(out + (size_t)t * 52);
        o4[0]  = mkf4(A.o0,  A.o1,  A.o2,  A.o3);
        o4[1]  = mkf4(A.o4,  A.o5,  A.o6,  A.o7);
        o4[2]  = mkf4(A.o8,  A.o9,  A.o10, A.o11);
        o4[3]  = mkf4(A.o12, B.o0,  B.o1,  B.o2);
        o4[4]  = mkf4(B.o3,  B.o4,  B.o5,  B.o6);
        o4[5]  = mkf4(B.o7,  B.o8,  B.o9,  B.o10);
        o4[6]  = mkf4(B.o11, B.o12, C.o0,  C.o1);
        o4[7]  = mkf4(C.o2,  C.o3,  C.o4,  C.o5);
        o4[8]  = mkf4(C.o6,  C.o7,  C.o8,  C.o9);
        o4[9]  = mkf4(C.o10, C.o11, C.o12, D.o0);
        o4[10] = mkf4(D.o1,  D.o2,  D.o3,  D.o4);
        o4[11] = mkf4(D.o5,  D.o6,  D.o7,  D.o8);
        o4[12] = mkf4(D.o9,  D.o10, D.o11, D.o12);
    } else {
        // tail: generic per-point scalar path
        for (int p = p0; p < N; ++p) {
            const int b = binding[p];
            const h8 rec = tab[b];
            const Out13 o = compute_point(
                xyz[3*p], xyz[3*p+1], xyz[3*p+2],
                rot[4*p], rot[4*p+1], rot[4*p+2], rot[4*p+3],
                scal[3*p], scal[3*p+1], scal[3*p+2],
                opac[p], fdc[3*p], fdc[3*p+1], fdc[3*p+2], rec);
            float* op = out + (size_t)p * 13;
            op[0] = o.o0;  op[1] = o.o1;  op[2]  = o.o2;  op[3]  = o.o3;
            op[4] = o.o4;  op[5] = o.o5;  op[6]  = o.o6;  op[7]  = o.o7;
            op[8] = o.o8;  op[9] = o.o9;  op[10] = o.o10; op[11] = o.o11;
            op[12] = o.o12;
        }
    }
}

// ---------------------------------------------------------------------------
// Fallback: fully fused single kernel (only if ws_size too small)
// ---------------------------------------------------------------------------
__global__ __launch_bounds__(BLK) void gauss_fused_kernel(
    const float* __restrict__ verts, const int* __restrict__ faces,
    const int* __restrict__ binding, const float* __restrict__ xyz,
    const float* __restrict__ rot, const float* __restrict__ scal,
    const float* __restrict__ opac, const float* __restrict__ fdc,
    float* __restrict__ out, int N)
{
    const int i = blockIdx.x * BLK + threadIdx.x;
    if (i >= N) return;
    const int b = binding[i];
    const int f0 = faces[3*b+0], f1 = faces[3*b+1], f2 = faces[3*b+2];
    const F3 v0 = f3(verts[3*f0], verts[3*f0+1], verts[3*f0+2]);
    const F3 v1 = f3(verts[3*f1], verts[3*f1+1], verts[3*f1+2]);
    const F3 v2 = f3(verts[3*f2], verts[3*f2+1], verts[3*f2+2]);
    const F3 fc  = mul(add(add(v0, v1), v2), (1.0f/3.0f));
    const F3 e01 = sub(v1, v0);
    const F3 e02 = sub(v2, v0);
    const F3 a0 = safe_normalize(e01);
    const F3 a1 = safe_normalize(cross3(a0, e02));
    const float s0 = sqrtf(dot3(e01, e01));
    const F3 a2 = mul(safe_normalize(cross3(a1, a0)), -1.0f);
    const float s1 = fabsf(dot3(a2, e02));
    const float fs = 0.5f * (s0 + s1);

    const float px = xyz[3*i], py = xyz[3*i+1], pz = xyz[3*i+2];
    const float qw0 = rot[4*i], qx0 = rot[4*i+1], qy0 = rot[4*i+2], qz0 = rot[4*i+3];
    const float sc0 = scal[3*i], sc1 = scal[3*i+1], sc2 = scal[3*i+2];
    const float opa = opac[i];
    const float d0 = fdc[3*i], d1 = fdc[3*i+1], d2 = fdc[3*i+2];

    F3 xo = add(add(mul(a0, px), mul(a1, py)), mul(a2, pz));
    xo = add(mul(xo, fs), fc);

    const float qn = sqrtf(qw0*qw0 + qx0*qx0 + qy0*qy0 + qz0*qz0) + 1e-12f;
    const float qi = 1.0f / qn;
    const float w = qw0*qi, x = qx0*qi, y = qy0*qi, z = qz0*qi;
    const float Q00 = 1.0f - 2.0f*(y*y + z*z);
    const float Q01 = 2.0f*(x*y - z*w);
    const float Q02 = 2.0f*(x*z + y*w);
    const float Q10 = 2.0f*(x*y + z*w);
    const float Q11 = 1.0f - 2.0f*(x*x + z*z);
    const float Q12 = 2.0f*(y*z - x*w);
    const float Q20 = 2.0f*(x*z - y*w);
    const float Q21 = 2.0f*(y*z + x*w);
    const float Q22 = 1.0f - 2.0f*(x*x + y*y);

    const F3 m0 = add(add(mul(a0, Q00), mul(a1, Q10)), mul(a2, Q20));
    const F3 m1 = add(add(mul(a0, Q01), mul(a1, Q11)), mul(a2, Q21));
    const F3 m2 = add(add(mul(a0, Q02), mul(a1, Q12)), mul(a2, Q22));

    const float w0 = __expf(sc0) * fs;
    const float w1 = __expf(sc1) * fs;
    const float w2 = __expf(sc2) * fs;
    const float t0s = w0*w0, t1s = w1*w1, t2s = w2*w2;

    float* op = out + (size_t)i * 13;
    op[0] = xo.x; op[1] = xo.y; op[2] = xo.z;
    op[3] = fminf(fmaxf((0.5f + 0.282f*d0) * 255.0f, 0.0f), 255.0f);
    op[4] = fminf(fmaxf((0.5f + 0.282f*d1) * 255.0f, 0.0f), 255.0f);
    op[5] = fminf(fmaxf((0.5f + 0.282f*d2) * 255.0f, 0.0f), 255.0f);
    op[6] = fminf(fmaxf((1.0f/(1.0f+__expf(-opa))) * 255.0f, 0.0f), 255.0f);
    op[7]  = t0s*m0.x*m0.x + t1s*m1.x*m1.x + t2s*m2.x*m2.x;
    op[8]  = t0s*m0.x*m0.y + t1s*m1.x*m1.y + t2s*m2.x*m2.y;
    op[9]  = t0s*m0.x*m0.z + t1s*m1.x*m1.z + t2s*m2.x*m2.z;
    op[10] = t0s*m0.y*m0.y + t1s*m1.y*m1.y + t2s*m2.y*m2.y;
    op[11] = t0s*m0.y*m0.z + t1s*m1.y*m1.z + t2s*m2.y*m2.z;
    op[12] = t0s*m0.z*m0.z + t1s*m1.z*m1.z + t2s*m2.z*m2.z;
}

extern "C" void kernel_launch(void* const* d_in, const int* in_sizes, int n_in,
                              void* d_out, int out_size, void* d_ws, size_t ws_size,
                              hipStream_t stream) {
    const float* verts   = (const float*)d_in[0];
    const int*   faces   = (const int*)  d_in[1];
    const int*   binding = (const int*)  d_in[2];
    const float* xyz     = (const float*)d_in[3];
    const float* rot     = (const float*)d_in[4];
    const float* scal    = (const float*)d_in[5];
    const float* opac    = (const float*)d_in[6];
    const float* fdc     = (const float*)d_in[7];
    // d_in[8] = features_rest: unused by the reference output
    float* out = (float*)d_out;
    const int N = in_sizes[2];
    const int F = in_sizes[1] / 3;

    const size_t tab_bytes = (size_t)F * sizeof(h8);

    if (ws_size >= tab_bytes) {
        h8* tab = (h8*)d_ws;
        const int fblocks = (F + BLK - 1) / BLK;
        face_precompute_kernel<<<fblocks, BLK, 0, stream>>>(verts, faces, tab, F);
        const int NT = (N + 3) / 4;
        const int blocks = (NT + BLK - 1) / BLK;
        gauss_main4_kernel<<<blocks, BLK, 0, stream>>>(
            tab, binding, xyz, rot, scal, opac, fdc, out, N);
    } else {
        const int blocks = (N + BLK - 1) / BLK;
        gauss_fused_kernel<<<blocks, BLK, 0, stream>>>(
            verts, faces, binding, xyz, rot, scal, opac, fdc, out, N);
    }
}

// Round 9
// 43.660 us; speedup vs baseline: 1.4594x; 1.4594x over previous
//
#include <hip/hip_runtime.h>
#include <math.h>

typedef float f4 __attribute__((ext_vector_type(4)));
typedef _Float16 h8 __attribute__((ext_vector_type(8)));

struct F3 { float x, y, z; };

__device__ __forceinline__ F3 f3(float x, float y, float z) { return {x, y, z}; }
__device__ __forceinline__ F3 add(F3 a, F3 b) { return {a.x+b.x, a.y+b.y, a.z+b.z}; }
__device__ __forceinline__ F3 sub(F3 a, F3 b) { return {a.x-b.x, a.y-b.y, a.z-b.z}; }
__device__ __forceinline__ F3 mul(F3 a, float s) { return {a.x*s, a.y*s, a.z*s}; }
__device__ __forceinline__ float dot3(F3 a, F3 b) { return a.x*b.x + a.y*b.y + a.z*b.z; }
__device__ __forceinline__ F3 cross3(F3 a, F3 b) {
    return {a.y*b.z - a.z*b.y, a.z*b.x - a.x*b.z, a.x*b.y - a.y*b.x};
}
__device__ __forceinline__ F3 safe_normalize(F3 a) {
    float d = dot3(a, a);
    float inv = rsqrtf(fmaxf(d, 1e-20f));
    return mul(a, inv);
}

#define BLK 256

// ---------------------------------------------------------------------------
// Kernel 1: per-face geometry -> ONE 16B record per face (8 x fp16):
//   { fc.x, fc.y, fc.z, fs, qw, qx, qy, qz }  with R(q) = [a0 | a1 | a2]
// 159 KB total: stays resident in every XCD's L2. One dwordx4 gather/point.
// fp16 rounding error ~1e-3 relative, vs absmax threshold 5.1 -> negligible.
// ---------------------------------------------------------------------------
__global__ __launch_bounds__(BLK) void face_precompute_kernel(
    const float* __restrict__ verts, const int* __restrict__ faces,
    h8* __restrict__ tab, int F)
{
    const int f = blockIdx.x * BLK + threadIdx.x;
    if (f >= F) return;
    const int f0 = faces[3*f+0], f1 = faces[3*f+1], f2 = faces[3*f+2];
    const F3 v0 = f3(verts[3*f0], verts[3*f0+1], verts[3*f0+2]);
    const F3 v1 = f3(verts[3*f1], verts[3*f1+1], verts[3*f1+2]);
    const F3 v2 = f3(verts[3*f2], verts[3*f2+1], verts[3*f2+2]);

    const F3 fc  = mul(add(add(v0, v1), v2), (1.0f/3.0f));
    const F3 e01 = sub(v1, v0);
    const F3 e02 = sub(v2, v0);
    const F3 a0 = safe_normalize(e01);
    const F3 a1 = safe_normalize(cross3(a0, e02));
    const F3 a2 = mul(safe_normalize(cross3(a1, a0)), -1.0f);
    const float s0 = sqrtf(dot3(e01, e01));
    const float s1 = fabsf(dot3(a2, e02));
    const float fs = 0.5f * (s0 + s1);

    // rotation matrix with columns a0,a1,a2 -> quaternion (w,x,y,z)
    const float R00 = a0.x, R10 = a0.y, R20 = a0.z;
    const float R01 = a1.x, R11 = a1.y, R21 = a1.z;
    const float R02 = a2.x, R12 = a2.y, R22 = a2.z;
    float qw, qx, qy, qz;
    const float tr = R00 + R11 + R22;
    if (tr > 0.0f) {
        const float s = 0.5f / sqrtf(tr + 1.0f);
        qw = 0.25f / s;
        qx = (R21 - R12) * s;
        qy = (R02 - R20) * s;
        qz = (R10 - R01) * s;
    } else if (R00 > R11 && R00 > R22) {
        const float s = 2.0f * sqrtf(1.0f + R00 - R11 - R22);
        qw = (R21 - R12) / s;
        qx = 0.25f * s;
        qy = (R01 + R10) / s;
        qz = (R02 + R20) / s;
    } else if (R11 > R22) {
        const float s = 2.0f * sqrtf(1.0f + R11 - R00 - R22);
        qw = (R02 - R20) / s;
        qx = (R01 + R10) / s;
        qy = 0.25f * s;
        qz = (R12 + R21) / s;
    } else {
        const float s = 2.0f * sqrtf(1.0f + R22 - R00 - R11);
        qw = (R10 - R01) / s;
        qx = (R02 + R20) / s;
        qy = (R12 + R21) / s;
        qz = 0.25f * s;
    }
    const float qn = rsqrtf(fmaxf(qw*qw + qx*qx + qy*qy + qz*qz, 1e-30f));
    qw *= qn; qx *= qn; qy *= qn; qz *= qn;

    h8 rec;
    rec[0] = (_Float16)fc.x; rec[1] = (_Float16)fc.y;
    rec[2] = (_Float16)fc.z; rec[3] = (_Float16)fs;
    rec[4] = (_Float16)qw;   rec[5] = (_Float16)qx;
    rec[6] = (_Float16)qy;   rec[7] = (_Float16)qz;
    tab[f] = rec;
}

// ---------------------------------------------------------------------------
// Kernel 2: 1 point/thread; ONE 16B face gather; stride-3 inputs staged via
// LDS as float4; output staged via LDS, flushed as coalesced float4.
// ---------------------------------------------------------------------------
__global__ __launch_bounds__(BLK) void gauss_main_kernel(
    const h8*    __restrict__ tab,       // (F,) 16B records
    const int*   __restrict__ binding,   // (N,)
    const float* __restrict__ xyz,       // (N,3)
    const float* __restrict__ rot,       // (N,4)
    const float* __restrict__ scal,      // (N,3)
    const float* __restrict__ opac,      // (N,1)
    const float* __restrict__ fdc,       // (N,1,3)
    float*       __restrict__ out,       // (N,13)
    int N)
{
    __shared__ float sin_[3 * BLK * 3];   // [xyz | scal | fdc], 768 floats each
    __shared__ float sout[BLK * 13];

    const int tid  = threadIdx.x;
    const int base = blockIdx.x * BLK;
    const int i    = base + tid;
    const int count = min(BLK, N - base);
    const bool full = (count == BLK);

    // gather-chain root first
    const int b = (i < N) ? binding[i] : 0;

    // the single face-record gather + per-point coalesced loads
    h8 rec = {0,0,0,0, (_Float16)1.0f,0,0,0};
    f4 q4 = {0,0,0,1};
    float opa = 0.0f;
    if (i < N) {
        rec = tab[b];
        q4  = reinterpret_cast<const f4*>(rot)[i];
        opa = opac[i];
    }

    if (full) {
        const f4* x4 = reinterpret_cast<const f4*>(xyz  + (size_t)base * 3);
        const f4* s4 = reinterpret_cast<const f4*>(scal + (size_t)base * 3);
        const f4* d4 = reinterpret_cast<const f4*>(fdc  + (size_t)base * 3);
        f4* sv = reinterpret_cast<f4*>(sin_);
        if (tid < 192) {               // 192 f4 per array
            sv[      tid] = x4[tid];
            sv[192 + tid] = s4[tid];
            sv[384 + tid] = d4[tid];
        }
    }

    float px, py, pz, sc0, sc1, sc2, d0, d1, d2;
    if (full) {
        __syncthreads();
        px  = sin_[        3*tid    ]; py  = sin_[        3*tid + 1]; pz  = sin_[        3*tid + 2];
        sc0 = sin_[ 768 +  3*tid    ]; sc1 = sin_[ 768 +  3*tid + 1]; sc2 = sin_[ 768 +  3*tid + 2];
        d0  = sin_[1536 +  3*tid    ]; d1  = sin_[1536 +  3*tid + 1]; d2  = sin_[1536 +  3*tid + 2];
    } else {
        px = py = pz = sc0 = sc1 = sc2 = d0 = d1 = d2 = 0.0f;
        if (i < N) {
            px  = xyz [3*i]; py  = xyz [3*i+1]; pz  = xyz [3*i+2];
            sc0 = scal[3*i]; sc1 = scal[3*i+1]; sc2 = scal[3*i+2];
            d0  = fdc [3*i]; d1  = fdc [3*i+1]; d2  = fdc [3*i+2];
        }
    }

    if (i < N) {
        const F3 fc = f3((float)rec[0], (float)rec[1], (float)rec[2]);
        const float fs = (float)rec[3];
        const float fw = (float)rec[4], fx = (float)rec[5];
        const float fy = (float)rec[6], fz = (float)rec[7];

        // xyz_out = (R(qf) * p) * fs + fc ;  v = p + qw*t + qv x t, t = 2 qv x p
        const F3 p  = f3(px, py, pz);
        const F3 qv = f3(fx, fy, fz);
        const F3 tt = mul(cross3(qv, p), 2.0f);
        const F3 v  = add(add(p, mul(tt, fw)), cross3(qv, tt));
        const F3 xo = add(mul(v, fs), fc);

        // normalize point quaternion (reference: q / (|q| + 1e-12))
        const float qn = sqrtf(q4.x*q4.x + q4.y*q4.y + q4.z*q4.z + q4.w*q4.w) + 1e-12f;
        const float qi = 1.0f / qn;
        const float pw = q4.x*qi, pxq = q4.y*qi, pyq = q4.z*qi, pzq = q4.w*qi;

        // compose qt = qf (Hamilton) qp  ->  R(qt) = O * Q
        const float tw = fw*pw  - fx*pxq - fy*pyq - fz*pzq;
        const float tx = fw*pxq + fx*pw  + fy*pzq - fz*pyq;
        const float ty = fw*pyq - fx*pzq + fy*pw  + fz*pxq;
        const float tz = fw*pzq + fx*pyq - fy*pxq + fz*pw;

        // M columns from qt
        const F3 m0 = f3(1.0f - 2.0f*(ty*ty + tz*tz),
                         2.0f*(tx*ty + tz*tw),
                         2.0f*(tx*tz - ty*tw));
        const F3 m1 = f3(2.0f*(tx*ty - tz*tw),
                         1.0f - 2.0f*(tx*tx + tz*tz),
                         2.0f*(ty*tz + tx*tw));
        const F3 m2 = f3(2.0f*(tx*tz + ty*tw),
                         2.0f*(ty*tz - tx*tw),
                         1.0f - 2.0f*(tx*tx + ty*ty));

        const float w0 = __expf(sc0) * fs;
        const float w1 = __expf(sc1) * fs;
        const float w2 = __expf(sc2) * fs;
        const float t0s = w0*w0, t1s = w1*w1, t2s = w2*w2;

        const float C00 = t0s*m0.x*m0.x + t1s*m1.x*m1.x + t2s*m2.x*m2.x;
        const float C01 = t0s*m0.x*m0.y + t1s*m1.x*m1.y + t2s*m2.x*m2.y;
        const float C02 = t0s*m0.x*m0.z + t1s*m1.x*m1.z + t2s*m2.x*m2.z;
        const float C11 = t0s*m0.y*m0.y + t1s*m1.y*m1.y + t2s*m2.y*m2.y;
        const float C12 = t0s*m0.y*m0.z + t1s*m1.y*m1.z + t2s*m2.y*m2.z;
        const float C22 = t0s*m0.z*m0.z + t1s*m1.z*m1.z + t2s*m2.z*m2.z;

        const float sg = 1.0f / (1.0f + __expf(-opa));

        float* s = sout + tid * 13;
        s[0]  = xo.x; s[1] = xo.y; s[2] = xo.z;
        s[3]  = fminf(fmaxf((0.5f + 0.282f*d0) * 255.0f, 0.0f), 255.0f);
        s[4]  = fminf(fmaxf((0.5f + 0.282f*d1) * 255.0f, 0.0f), 255.0f);
        s[5]  = fminf(fmaxf((0.5f + 0.282f*d2) * 255.0f, 0.0f), 255.0f);
        s[6]  = fminf(fmaxf(sg * 255.0f, 0.0f), 255.0f);
        s[7]  = C00; s[8] = C01; s[9] = C02; s[10] = C11; s[11] = C12; s[12] = C22;
    }

    __syncthreads();

    // coalesced float4 flush of the block's contiguous output span
    const int total = count * 13;
    const size_t obase = (size_t)base * 13;
    const int n4 = total >> 2;
    const f4* sf = reinterpret_cast<const f4*>(sout);
    f4* o4 = reinterpret_cast<f4*>(out + obase);
    for (int j = tid; j < n4; j += BLK) o4[j] = sf[j];
    for (int j = (n4 << 2) + tid; j < total; j += BLK) out[obase + j] = sout[j];
}

// ---------------------------------------------------------------------------
// Fallback: fully fused single kernel (only if ws_size too small)
// ---------------------------------------------------------------------------
__global__ __launch_bounds__(BLK) void gauss_fused_kernel(
    const float* __restrict__ verts, const int* __restrict__ faces,
    const int* __restrict__ binding, const float* __restrict__ xyz,
    const float* __restrict__ rot, const float* __restrict__ scal,
    const float* __restrict__ opac, const float* __restrict__ fdc,
    float* __restrict__ out, int N)
{
    const int i = blockIdx.x * BLK + threadIdx.x;
    if (i >= N) return;
    const int b = binding[i];
    const int f0 = faces[3*b+0], f1 = faces[3*b+1], f2 = faces[3*b+2];
    const F3 v0 = f3(verts[3*f0], verts[3*f0+1], verts[3*f0+2]);
    const F3 v1 = f3(verts[3*f1], verts[3*f1+1], verts[3*f1+2]);
    const F3 v2 = f3(verts[3*f2], verts[3*f2+1], verts[3*f2+2]);
    const F3 fc  = mul(add(add(v0, v1), v2), (1.0f/3.0f));
    const F3 e01 = sub(v1, v0);
    const F3 e02 = sub(v2, v0);
    const F3 a0 = safe_normalize(e01);
    const F3 a1 = safe_normalize(cross3(a0, e02));
    const float s0 = sqrtf(dot3(e01, e01));
    const F3 a2 = mul(safe_normalize(cross3(a1, a0)), -1.0f);
    const float s1 = fabsf(dot3(a2, e02));
    const float fs = 0.5f * (s0 + s1);

    const float px = xyz[3*i], py = xyz[3*i+1], pz = xyz[3*i+2];
    const float qw0 = rot[4*i], qx0 = rot[4*i+1], qy0 = rot[4*i+2], qz0 = rot[4*i+3];
    const float sc0 = scal[3*i], sc1 = scal[3*i+1], sc2 = scal[3*i+2];
    const float opa = opac[i];
    const float d0 = fdc[3*i], d1 = fdc[3*i+1], d2 = fdc[3*i+2];

    F3 xo = add(add(mul(a0, px), mul(a1, py)), mul(a2, pz));
    xo = add(mul(xo, fs), fc);

    const float qn = sqrtf(qw0*qw0 + qx0*qx0 + qy0*qy0 + qz0*qz0) + 1e-12f;
    const float qi = 1.0f / qn;
    const float w = qw0*qi, x = qx0*qi, y = qy0*qi, z = qz0*qi;
    const float Q00 = 1.0f - 2.0f*(y*y + z*z);
    const float Q01 = 2.0f*(x*y - z*w);
    const float Q02 = 2.0f*(x*z + y*w);
    const float Q10 = 2.0f*(x*y + z*w);
    const float Q11 = 1.0f - 2.0f*(x*x + z*z);
    const float Q12 = 2.0f*(y*z - x*w);
    const float Q20 = 2.0f*(x*z - y*w);
    const float Q21 = 2.0f*(y*z + x*w);
    const float Q22 = 1.0f - 2.0f*(x*x + y*y);

    const F3 m0 = add(add(mul(a0, Q00), mul(a1, Q10)), mul(a2, Q20));
    const F3 m1 = add(add(mul(a0, Q01), mul(a1, Q11)), mul(a2, Q21));
    const F3 m2 = add(add(mul(a0, Q02), mul(a1, Q12)), mul(a2, Q22));

    const float w0 = __expf(sc0) * fs;
    const float w1 = __expf(sc1) * fs;
    const float w2 = __expf(sc2) * fs;
    const float t0s = w0*w0, t1s = w1*w1, t2s = w2*w2;

    float* op = out + (size_t)i * 13;
    op[0] = xo.x; op[1] = xo.y; op[2] = xo.z;
    op[3] = fminf(fmaxf((0.5f + 0.282f*d0) * 255.0f, 0.0f), 255.0f);
    op[4] = fminf(fmaxf((0.5f + 0.282f*d1) * 255.0f, 0.0f), 255.0f);
    op[5] = fminf(fmaxf((0.5f + 0.282f*d2) * 255.0f, 0.0f), 255.0f);
    op[6] = fminf(fmaxf((1.0f/(1.0f+__expf(-opa))) * 255.0f, 0.0f), 255.0f);
    op[7]  = t0s*m0.x*m0.x + t1s*m1.x*m1.x + t2s*m2.x*m2.x;
    op[8]  = t0s*m0.x*m0.y + t1s*m1.x*m1.y + t2s*m2.x*m2.y;
    op[9]  = t0s*m0.x*m0.z + t1s*m1.x*m1.z + t2s*m2.x*m2.z;
    op[10] = t0s*m0.y*m0.y + t1s*m1.y*m1.y + t2s*m2.y*m2.y;
    op[11] = t0s*m0.y*m0.z + t1s*m1.y*m1.z + t2s*m2.y*m2.z;
    op[12] = t0s*m0.z*m0.z + t1s*m1.z*m1.z + t2s*m2.z*m2.z;
}

extern "C" void kernel_launch(void* const* d_in, const int* in_sizes, int n_in,
                              void* d_out, int out_size, void* d_ws, size_t ws_size,
                              hipStream_t stream) {
    const float* verts   = (const float*)d_in[0];
    const int*   faces   = (const int*)  d_in[1];
    const int*   binding = (const int*)  d_in[2];
    const float* xyz     = (const float*)d_in[3];
    const float* rot     = (const float*)d_in[4];
    const float* scal    = (const float*)d_in[5];
    const float* opac    = (const float*)d_in[6];
    const float* fdc     = (const float*)d_in[7];
    // d_in[8] = features_rest: unused by the reference output
    float* out = (float*)d_out;
    const int N = in_sizes[2];
    const int F = in_sizes[1] / 3;

    const size_t tab_bytes = (size_t)F * sizeof(h8);
    const int blocks = (N + BLK - 1) / BLK;

    if (ws_size >= tab_bytes) {
        h8* tab = (h8*)d_ws;
        const int fblocks = (F + BLK - 1) / BLK;
        face_precompute_kernel<<<fblocks, BLK, 0, stream>>>(verts, faces, tab, F);
        gauss_main_kernel<<<blocks, BLK, 0, stream>>>(
            tab, binding, xyz, rot, scal, opac, fdc, out, N);
    } else {
        gauss_fused_kernel<<<blocks, BLK, 0, stream>>>(
            verts, faces, binding, xyz, rot, scal, opac, fdc, out, N);
    }
}